// Round 2
// 125.663 us; speedup vs baseline: 1.0899x; 1.0899x over previous
//
#include <hip/hip_runtime.h>
#include <hip/hip_bf16.h>

// Problem: x(4,256,64,64), offset(4,18,64,64), mask(4,9,64,64),
// weight(256,256,3,3) -> out(4,256,64,64). stride=1, pad=1, K=3.
// R12 = R11 resubmit (R11 bench was an infra failure: "container failed
// twice", no pytest/absmax signal; source re-audited, no defect found).
// R11: descriptor-precompute + T14 prefetch.
// R10 post-mortem: fused was VALU+serialization bound (VALUBusy 37%,
// MfmaUtil 11%, HBM 9%). Two costs: (a) wave-uniform bilinear setup
// (~35 VALU/m, duplicated across all 64 lanes, FP so no SALU), (b) the
// gather->combine->barrier->MFMA serial chain per kk with only 2 blocks/CU.
// Now: prep precomputes per-(m,kk) descriptors {int4 corner-base, float4
// mask-folded weight}; fused stages its 9KB of descriptors in LDS once,
// and per kk issues the NEXT kk's corner gathers into registers before the
// barrier so their latency hides under the MFMA phase (T14). Combine uses
// dword shift/mask unpack + float2 vector FMA. setprio(1) wraps MFMA (T5).
#define CN 256
#define HN 64
#define WN 64
#define ON 256
#define KKN 9
#define HWN 4096
#define KDIM 2304   // 9*256
#define KC 288      // KDIM/8 chunks

using frag_ab = __attribute__((ext_vector_type(8))) short;  // 8 bf16
using frag_cd = __attribute__((ext_vector_type(4))) float;  // 4 fp32
using short4v = __attribute__((ext_vector_type(4))) short;  // 4 bf16 (8B)
using int4v   = __attribute__((ext_vector_type(4))) int;
using float4v = __attribute__((ext_vector_type(4))) float;
using float2v = __attribute__((ext_vector_type(2))) float;
using uint2v  = __attribute__((ext_vector_type(2))) unsigned;

static __device__ inline short f2bf(float f) {
    union { float f; unsigned u; } v; v.f = f;
    unsigned r = v.u + 0x7fffu + ((v.u >> 16) & 1u);
    return (short)(r >> 16);
}

// ---------- kernel 1: prep = transpose x -> BHWC bf16 | repack weight |
// ----------            precompute bilinear descriptors ------------------
__global__ __launch_bounds__(256) void prep_kernel(const float* __restrict__ x,
                                                   const float* __restrict__ wsrc,
                                                   const float* __restrict__ offs,
                                                   const float* __restrict__ maskp,
                                                   short* __restrict__ xb16,
                                                   short* __restrict__ wtb,
                                                   int* __restrict__ descg) {
    int bidx = blockIdx.x;
    int tid  = threadIdx.x;
    if (bidx < 1024) {
        __shared__ float tile[64][65];
        int b   = bidx >> 8;
        int rem = bidx & 255;
        int c0  = (rem >> 6) * 64;
        int p0  = (rem & 63) * 64;
        int tp = tid & 63, tc = tid >> 6;
        for (int i = 0; i < 16; ++i) {
            int c = tc + i * 4;
            tile[c][tp] = x[(b * CN + c0 + c) * HWN + p0 + tp];
        }
        __syncthreads();
        int tcc = tid & 63, tpp = tid >> 6;
        for (int i = 0; i < 16; ++i) {
            int p = tpp + i * 4;
            xb16[(b * HWN + p0 + p) * CN + c0 + tcc] = f2bf(tile[tcc][p]);
        }
    } else if (bidx < 1312) {
        int chunk = (bidx - 1024) * 256 + tid;   // < 4*288*64 = 73728
        int ob  = chunk / (KC * 64);
        int rem = chunk - ob * (KC * 64);
        int kc  = rem >> 6;
        int row = rem & 63;
        int o   = ob * 64 + row;
        int kk  = kc >> 5;
        int oct = kc & 31;
        frag_ab v;
        #pragma unroll
        for (int e = 0; e < 8; ++e)
            v[e] = f2bf(wsrc[(o * CN + oct * 8 + e) * 9 + kk]);
        *(frag_ab*)&wtb[(size_t)chunk * 8] = v;
    } else {
        // descriptor precompute: u indexes (kk, m) with m = b*4096 + h*64 + w
        int u  = (bidx - 1312) * 256 + tid;      // < 9*16384 = 147456
        int kk = u >> 14;
        int m  = u & 16383;
        int b  = m >> 12;
        int p  = m & 4095;
        int h  = p >> 6;
        int w  = p & 63;
        int ki = kk / 3, kj = kk - ki * 3;
        float dy = offs[(b * 18 + 2 * kk) * HWN + p];
        float dx = offs[(b * 18 + 2 * kk + 1) * HWN + p];
        float mv = maskp[(b * 9 + kk) * HWN + p];
        float py = (float)(h - 1 + ki) + dy;
        float px = (float)(w - 1 + kj) + dx;
        float y0f = floorf(py), x0f = floorf(px);
        float wy = py - y0f, wx = px - x0f;
        int y0 = (int)y0f, x0 = (int)x0f;
        int4v cb; float4v cw;
        #pragma unroll
        for (int cy = 0; cy < 2; ++cy)
            #pragma unroll
            for (int cx = 0; cx < 2; ++cx) {
                int yy = y0 + cy, xx = x0 + cx;
                bool valid = (yy >= 0 && yy < HN && xx >= 0 && xx < WN);
                int yc = min(max(yy, 0), HN - 1);
                int xc = min(max(xx, 0), WN - 1);
                cb[cy * 2 + cx] = ((b * HN + yc) * WN + xc) * CN;
                float wgt = (cy ? wy : 1.f - wy) * (cx ? wx : 1.f - wx) * mv;
                cw[cy * 2 + cx] = valid ? wgt : 0.f;
            }
        int* dd = descg + (size_t)u * 8;
        *(int4v*)dd       = cb;
        *(float4v*)(dd + 4) = cw;
    }
}

// ---------- kernel 2: fused sample + GEMM ----------
// block: 32 m-rows (m0 = bid*32) x 256 o-cols, 4 waves (wave wv: cols
// wv*64..+64). Per kk: combine previously-prefetched corner rows with LDS
// descriptor weights -> A-tile (oct-stride-33 padded layout), prefetch
// kk+1's 32 coalesced corner-row gathers into regs, barrier, MFMA.
__global__ __launch_bounds__(256, 2) void fused_kernel(const short* __restrict__ xb16,
                                                       const short* __restrict__ wtb,
                                                       const int* __restrict__ descg,
                                                       float* __restrict__ out) {
    __shared__ struct {
        union {
            short Ab[2][8448];        // 2 x 16.5 KB A-tile (padded chunks)
            float outb[32 * 257];     // epilogue transpose, pad 257
        } mix;
        int desc[2304];               // 9 kk x 32 m x 8 dwords = 9216 B
    } sm;
    int tid  = threadIdx.x;
    int m0   = blockIdx.x * 32;
    int b    = m0 >> 12;
    int h    = (m0 >> 6) & 63;
    int w0   = m0 & 63;               // 0 or 32
    int wv   = __builtin_amdgcn_readfirstlane(tid >> 6);
    int lane = tid & 63;
    int q    = lane >> 4, r = lane & 15;
    // sampling write base (shorts): chunk 33*(lane>>1), half (lane&1)
    int wbase = 33 * (lane >> 1) * 8 + (lane & 1) * 4;
    int lane4 = lane * 4;
    int wv8   = wv * 8;

    // stage this block's descriptors into LDS (coalesced, once)
    #pragma unroll
    for (int kk = 0; kk < KKN; ++kk)
        sm.desc[kk * 256 + tid] = descg[((size_t)kk * 16384 + m0) * 8 + tid];
    __syncthreads();

    frag_cd acc[2][4];
    #pragma unroll
    for (int i = 0; i < 2; ++i)
        #pragma unroll
        for (int j = 0; j < 4; ++j)
            acc[i][j] = (frag_cd){0.f, 0.f, 0.f, 0.f};

    short4v stg[8][4];    // prefetched corner rows (64 VGPR)
    float4v cwc[8];       // corner weights for the prefetched kk

    auto prefetch = [&](int kk1) {
        #pragma unroll
        for (int i = 0; i < 8; ++i) {
            int dbase = (kk1 * 32 + wv8 + i) * 8;     // wave-uniform -> bcast
            int4v cb = *(const int4v*)&sm.desc[dbase];
            cwc[i]   = *(const float4v*)&sm.desc[dbase + 4];
            #pragma unroll
            for (int c = 0; c < 4; ++c)               // coalesced 512B rows
                stg[i][c] = *(const short4v*)&xb16[cb[c] + lane4];
        }
    };

    prefetch(0);

    for (int kk = 0; kk < KKN; ++kk) {
        short* dst = sm.mix.Ab[kk & 1];
        // ---- combine phase: weighted 4-corner sum -> bf16 A-tile ----
        #pragma unroll
        for (int i = 0; i < 8; ++i) {
            float4v cw = cwc[i];
            short4v res;
            #pragma unroll
            for (int g = 0; g < 2; ++g) {             // channel pairs
                float2v a = (float2v){0.f, 0.f};
                #pragma unroll
                for (int c = 0; c < 4; ++c) {
                    uint2v uv = __builtin_bit_cast(uint2v, stg[i][c]);
                    unsigned uu = uv[g];
                    float2v f;
                    f.x = __builtin_bit_cast(float, uu << 16);
                    f.y = __builtin_bit_cast(float, uu & 0xffff0000u);
                    a += f * cw[c];
                }
                __hip_bfloat162 p2 = __float22bfloat162_rn(make_float2(a.x, a.y));
                res[2 * g]     = *(short*)&p2.x;
                res[2 * g + 1] = *(short*)&p2.y;
            }
            *(short4v*)&dst[wbase + (wv8 + i) * 8] = res;   // ds_write_b64
        }
        // ---- T14: issue next kk's gathers; latency hides under MFMA ----
        if (kk < 8) prefetch(kk + 1);
        __syncthreads();
        // ---- MFMA phase: 8 k16-steps; A from LDS, B direct global (L2) --
        #pragma unroll
        for (int ks = 0; ks < 8; ++ks) {
            frag_ab af[2], bf[4];
            #pragma unroll
            for (int i = 0; i < 2; ++i)
                af[i] = *(const frag_ab*)
                    &dst[(33 * (ks * 4 + q) + i * 16 + r) * 8];
            #pragma unroll
            for (int j = 0; j < 4; ++j)
                bf[j] = *(const frag_ab*)
                    &wtb[(((size_t)wv * KC + kk * 32 + ks * 4 + q) * 64
                          + j * 16 + r) * 8];
            __builtin_amdgcn_s_setprio(1);
            #pragma unroll
            for (int i = 0; i < 2; ++i)
                #pragma unroll
                for (int j = 0; j < 4; ++j)
                    acc[i][j] = __builtin_amdgcn_mfma_f32_16x16x32_bf16(
                        af[i], bf[j], acc[i][j], 0, 0, 0);
            __builtin_amdgcn_s_setprio(0);
        }
        // no trailing barrier: next kk writes the other buffer; the barrier
        // at kk+1 orders mfma(kk) before any combine(kk+2) buffer reuse.
    }
    __syncthreads();

    // ---- epilogue: acc (row=i*16+q*4+reg, col=wv*64+j*16+r) -> LDS -> BOHW
    #pragma unroll
    for (int i = 0; i < 2; ++i)
        #pragma unroll
        for (int j = 0; j < 4; ++j) {
            int ml = i * 16 + q * 4;
            int ol = wv * 64 + j * 16 + r;
            sm.mix.outb[(ml + 0) * 257 + ol] = acc[i][j][0];
            sm.mix.outb[(ml + 1) * 257 + ol] = acc[i][j][1];
            sm.mix.outb[(ml + 2) * 257 + ol] = acc[i][j][2];
            sm.mix.outb[(ml + 3) * 257 + ol] = acc[i][j][3];
        }
    __syncthreads();
    {
        int ww = tid & 31;        // width within tile
        int og = tid >> 5;        // 0..7
        #pragma unroll
        for (int oo = 0; oo < 32; ++oo) {
            int o = oo * 8 + og;
            out[(((size_t)b * ON + o) * HN + h) * WN + w0 + ww] =
                sm.mix.outb[ww * 257 + o];
        }
    }
}

extern "C" void kernel_launch(void* const* d_in, const int* in_sizes, int n_in,
                              void* d_out, int out_size, void* d_ws, size_t ws_size,
                              hipStream_t stream) {
    const float* x      = (const float*)d_in[0];
    const float* offset = (const float*)d_in[1];
    const float* mask   = (const float*)d_in[2];
    const float* weight = (const float*)d_in[3];
    float* out = (float*)d_out;

    // ws: xb16 bf16 8 MiB | wtb (B') bf16 1.125 MiB | desc 4.5 MiB
    short* xb16  = (short*)d_ws;
    short* wtb   = (short*)((char*)d_ws + 8388608);
    int*   descg = (int*)((char*)d_ws + 9568256);

    hipLaunchKernelGGL(prep_kernel,  dim3(1888), dim3(256), 0, stream,
                       x, weight, offset, mask, xb16, wtb, descg);
    hipLaunchKernelGGL(fused_kernel, dim3(512),  dim3(256), 0, stream,
                       xb16, wtb, descg, out);
}

// Round 3
// 121.254 us; speedup vs baseline: 1.1296x; 1.0364x over previous
//
#include <hip/hip_runtime.h>
#include <hip/hip_bf16.h>

// Problem: x(4,256,64,64), offset(4,18,64,64), mask(4,9,64,64),
// weight(256,256,3,3) -> out(4,256,64,64). stride=1, pad=1, K=3.
// R13: 8-wave blocks (32 cols/wave) + in-kernel descriptor compute.
// R12 post-mortem (matched): desc-hoist+T14 took fused 69->54us. Counters
// now: MfmaUtil 13%, VALUBusy 22%, HBM 12%, Occ 18.5% -> latency-bound,
// only 2 waves/SIMD (grid 512 x 4 waves = 2 blocks/CU). Fix: same 32x256
// block but 512 threads / 8 waves (acc 2x2/wave, 4 sample rows/wave) ->
// 4 waves/SIMD, half the per-thread serial work, same totals. Descriptors
// (288/block) now computed one-time inside fused (threads 0..287) straight
// into LDS -> prep desc branch + 9.3MB global round-trip deleted.
#define CN 256
#define HN 64
#define WN 64
#define ON 256
#define KKN 9
#define HWN 4096
#define KDIM 2304   // 9*256
#define KC 288      // KDIM/8 chunks

using frag_ab = __attribute__((ext_vector_type(8))) short;  // 8 bf16
using frag_cd = __attribute__((ext_vector_type(4))) float;  // 4 fp32
using short4v = __attribute__((ext_vector_type(4))) short;  // 4 bf16 (8B)
using int4v   = __attribute__((ext_vector_type(4))) int;
using float4v = __attribute__((ext_vector_type(4))) float;
using float2v = __attribute__((ext_vector_type(2))) float;
using uint2v  = __attribute__((ext_vector_type(2))) unsigned;

static __device__ inline short f2bf(float f) {
    union { float f; unsigned u; } v; v.f = f;
    unsigned r = v.u + 0x7fffu + ((v.u >> 16) & 1u);
    return (short)(r >> 16);
}

// ---------- kernel 1: prep = transpose x -> BHWC bf16 | repack weight ----
__global__ __launch_bounds__(256) void prep_kernel(const float* __restrict__ x,
                                                   const float* __restrict__ wsrc,
                                                   short* __restrict__ xb16,
                                                   short* __restrict__ wtb) {
    int bidx = blockIdx.x;
    int tid  = threadIdx.x;
    if (bidx < 1024) {
        __shared__ float tile[64][65];
        int b   = bidx >> 8;
        int rem = bidx & 255;
        int c0  = (rem >> 6) * 64;
        int p0  = (rem & 63) * 64;
        int tp = tid & 63, tc = tid >> 6;
        for (int i = 0; i < 16; ++i) {
            int c = tc + i * 4;
            tile[c][tp] = x[(b * CN + c0 + c) * HWN + p0 + tp];
        }
        __syncthreads();
        int tcc = tid & 63, tpp = tid >> 6;
        for (int i = 0; i < 16; ++i) {
            int p = tpp + i * 4;
            xb16[(b * HWN + p0 + p) * CN + c0 + tcc] = f2bf(tile[tcc][p]);
        }
    } else {
        int chunk = (bidx - 1024) * 256 + tid;   // < 4*288*64 = 73728
        int ob  = chunk / (KC * 64);
        int rem = chunk - ob * (KC * 64);
        int kc  = rem >> 6;
        int row = rem & 63;
        int o   = ob * 64 + row;
        int kk  = kc >> 5;
        int oct = kc & 31;
        frag_ab v;
        #pragma unroll
        for (int e = 0; e < 8; ++e)
            v[e] = f2bf(wsrc[(o * CN + oct * 8 + e) * 9 + kk]);
        *(frag_ab*)&wtb[(size_t)chunk * 8] = v;
    }
}

// ---------- kernel 2: fused sample + GEMM ----------
// block: 32 m-rows (m0 = bid*32) x 256 o-cols, 8 waves (wave wv: cols
// wv*32..+32, sample rows wv*4..+4). Per kk: combine prefetched corner
// rows -> A-tile (oct-stride-33), prefetch kk+1 gathers (T14), barrier,
// MFMA (A from LDS, B direct from L2-resident wtb). setprio around MFMA.
__global__ __launch_bounds__(512, 4) void fused_kernel(const short* __restrict__ xb16,
                                                       const short* __restrict__ wtb,
                                                       const float* __restrict__ offs,
                                                       const float* __restrict__ maskp,
                                                       float* __restrict__ out) {
    __shared__ struct {
        union {
            short Ab[2][8448];        // 2 x 16.5 KB A-tile (padded chunks)
            float outb[32 * 257];     // epilogue transpose, pad 257
        } mix;
        int desc[2304];               // 9 kk x 32 m x 8 dwords = 9216 B
    } sm;
    int tid  = threadIdx.x;
    int m0   = blockIdx.x * 32;
    int b    = m0 >> 12;
    int h    = (m0 >> 6) & 63;
    int w0   = m0 & 63;               // 0 or 32
    int wv   = __builtin_amdgcn_readfirstlane(tid >> 6);   // 0..7
    int lane = tid & 63;
    int q    = lane >> 4, r = lane & 15;
    // sampling write base (shorts): chunk 33*(lane>>1), half (lane&1)
    int wbase = 33 * (lane >> 1) * 8 + (lane & 1) * 4;
    int lane4 = lane * 4;
    int wv4   = wv * 4;

    // ---- one-time descriptor compute: thread t<288 -> desc (kk, m) ----
    if (tid < 288) {
        int kk = tid >> 5;
        int m  = tid & 31;
        int wc = w0 + m;
        int p  = h * 64 + wc;
        int ki = kk / 3, kj = kk - ki * 3;
        float dy = offs[(b * 18 + 2 * kk) * HWN + p];
        float dx = offs[(b * 18 + 2 * kk + 1) * HWN + p];
        float mv = maskp[(b * 9 + kk) * HWN + p];
        float py = (float)(h - 1 + ki) + dy;
        float px = (float)(wc - 1 + kj) + dx;
        float y0f = floorf(py), x0f = floorf(px);
        float wy = py - y0f, wx = px - x0f;
        int y0 = (int)y0f, x0 = (int)x0f;
        int4v cb; float4v cw;
        #pragma unroll
        for (int cy = 0; cy < 2; ++cy)
            #pragma unroll
            for (int cx = 0; cx < 2; ++cx) {
                int yy = y0 + cy, xx = x0 + cx;
                bool valid = (yy >= 0 && yy < HN && xx >= 0 && xx < WN);
                int yc = min(max(yy, 0), HN - 1);
                int xc = min(max(xx, 0), WN - 1);
                cb[cy * 2 + cx] = ((b * HN + yc) * WN + xc) * CN;
                float wgt = (cy ? wy : 1.f - wy) * (cx ? wx : 1.f - wx) * mv;
                cw[cy * 2 + cx] = valid ? wgt : 0.f;
            }
        int* dd = &sm.desc[tid * 8];
        *(int4v*)dd       = cb;
        *(float4v*)(dd + 4) = cw;
    }
    __syncthreads();

    frag_cd acc[2][2];
    #pragma unroll
    for (int i = 0; i < 2; ++i)
        #pragma unroll
        for (int j = 0; j < 2; ++j)
            acc[i][j] = (frag_cd){0.f, 0.f, 0.f, 0.f};

    short4v stg[4][4];    // prefetched corner rows (32 VGPR)
    float4v cwc[4];       // corner weights for the prefetched kk

    auto prefetch = [&](int kk1) {
        #pragma unroll
        for (int i = 0; i < 4; ++i) {
            int dbase = (kk1 * 32 + wv4 + i) * 8;     // wave-uniform -> bcast
            int4v cb = *(const int4v*)&sm.desc[dbase];
            cwc[i]   = *(const float4v*)&sm.desc[dbase + 4];
            #pragma unroll
            for (int c = 0; c < 4; ++c)               // coalesced 512B rows
                stg[i][c] = *(const short4v*)&xb16[cb[c] + lane4];
        }
    };

    prefetch(0);

    int jb = (wv & 1) * 2;        // col sub-pair within the 64-col group
    int ob = wv >> 1;             // 64-col group 0..3
    for (int kk = 0; kk < KKN; ++kk) {
        short* dst = sm.mix.Ab[kk & 1];
        // ---- combine phase: weighted 4-corner sum -> bf16 A-tile ----
        #pragma unroll
        for (int i = 0; i < 4; ++i) {
            float4v cw = cwc[i];
            short4v res;
            #pragma unroll
            for (int g = 0; g < 2; ++g) {             // channel pairs
                float2v a = (float2v){0.f, 0.f};
                #pragma unroll
                for (int c = 0; c < 4; ++c) {
                    uint2v uv = __builtin_bit_cast(uint2v, stg[i][c]);
                    unsigned uu = uv[g];
                    float2v f;
                    f.x = __builtin_bit_cast(float, uu << 16);
                    f.y = __builtin_bit_cast(float, uu & 0xffff0000u);
                    a += f * cw[c];
                }
                __hip_bfloat162 p2 = __float22bfloat162_rn(make_float2(a.x, a.y));
                res[2 * g]     = *(short*)&p2.x;
                res[2 * g + 1] = *(short*)&p2.y;
            }
            *(short4v*)&dst[wbase + (wv4 + i) * 8] = res;   // ds_write_b64
        }
        // ---- T14: issue next kk's gathers; latency hides under MFMA ----
        if (kk < 8) prefetch(kk + 1);
        __syncthreads();
        // ---- MFMA phase: 8 k16-steps; A from LDS, B direct global (L2) --
        #pragma unroll
        for (int ks = 0; ks < 8; ++ks) {
            frag_ab af[2], bf[2];
            #pragma unroll
            for (int i = 0; i < 2; ++i)
                af[i] = *(const frag_ab*)
                    &dst[(33 * (ks * 4 + q) + i * 16 + r) * 8];
            #pragma unroll
            for (int j = 0; j < 2; ++j)
                bf[j] = *(const frag_ab*)
                    &wtb[(((size_t)ob * KC + kk * 32 + ks * 4 + q) * 64
                          + (jb + j) * 16 + r) * 8];
            __builtin_amdgcn_s_setprio(1);
            #pragma unroll
            for (int i = 0; i < 2; ++i)
                #pragma unroll
                for (int j = 0; j < 2; ++j)
                    acc[i][j] = __builtin_amdgcn_mfma_f32_16x16x32_bf16(
                        af[i], bf[j], acc[i][j], 0, 0, 0);
            __builtin_amdgcn_s_setprio(0);
        }
        // no trailing barrier: next kk writes the other buffer; the barrier
        // at kk+1 orders mfma(kk) before any combine(kk+2) buffer reuse.
    }
    __syncthreads();

    // ---- epilogue: acc (row=i*16+q*4+reg, col=wv*32+j*16+r) -> LDS -> BOHW
    #pragma unroll
    for (int i = 0; i < 2; ++i)
        #pragma unroll
        for (int j = 0; j < 2; ++j) {
            int ml = i * 16 + q * 4;
            int ol = wv * 32 + j * 16 + r;
            sm.mix.outb[(ml + 0) * 257 + ol] = acc[i][j][0];
            sm.mix.outb[(ml + 1) * 257 + ol] = acc[i][j][1];
            sm.mix.outb[(ml + 2) * 257 + ol] = acc[i][j][2];
            sm.mix.outb[(ml + 3) * 257 + ol] = acc[i][j][3];
        }
    __syncthreads();
    {
        int ww = tid & 31;        // width within tile
        int og = tid >> 5;        // 0..15
        #pragma unroll
        for (int oo = 0; oo < 16; ++oo) {
            int o = oo * 16 + og;
            out[(((size_t)b * ON + o) * HN + h) * WN + w0 + ww] =
                sm.mix.outb[ww * 257 + o];
        }
    }
}

extern "C" void kernel_launch(void* const* d_in, const int* in_sizes, int n_in,
                              void* d_out, int out_size, void* d_ws, size_t ws_size,
                              hipStream_t stream) {
    const float* x      = (const float*)d_in[0];
    const float* offset = (const float*)d_in[1];
    const float* mask   = (const float*)d_in[2];
    const float* weight = (const float*)d_in[3];
    float* out = (float*)d_out;

    // ws: xb16 bf16 8 MiB | wtb (B') bf16 1.125 MiB
    short* xb16 = (short*)d_ws;
    short* wtb  = (short*)((char*)d_ws + 8388608);

    hipLaunchKernelGGL(prep_kernel,  dim3(1312), dim3(256), 0, stream,
                       x, weight, xb16, wtb);
    hipLaunchKernelGGL(fused_kernel, dim3(512),  dim3(512), 0, stream,
                       xb16, wtb, offset, mask, out);
}

// Round 4
// 118.455 us; speedup vs baseline: 1.1562x; 1.0236x over previous
//
#include <hip/hip_runtime.h>
#include <hip/hip_bf16.h>

// Problem: x(4,256,64,64), offset(4,18,64,64), mask(4,9,64,64),
// weight(256,256,3,3) -> out(4,256,64,64). stride=1, pad=1, K=3.
// R14: non-draining barriers + explicit 2-ahead B pipeline.
// R13 post-mortem (MISSED): occupancy 2x'd but time 54->51us only. Cause:
// (a) __syncthreads drains vmcnt(0) -> T14 prefetch completed AT barrier,
// never hidden under MFMA; (b) VGPR=56 shows per-ks B loads were issued
// at use (L2 ~200cyc exposed per ks). Fix: lgkmcnt(0)+raw s_barrier keeps
// global loads in flight across barriers (m201 pattern); bfx[2] ring with
// B(ks0,ks1) issued at top of kk (OLDER than stg prefetch, so bf-waits
// don't drain stg - vmcnt retires in order) and ks+2 reloads after each
// MFMA quad. setprio(1) around MFMA quads (T5).
#define CN 256
#define HN 64
#define WN 64
#define ON 256
#define KKN 9
#define HWN 4096
#define KDIM 2304   // 9*256
#define KC 288      // KDIM/8 chunks

using frag_ab = __attribute__((ext_vector_type(8))) short;  // 8 bf16
using frag_cd = __attribute__((ext_vector_type(4))) float;  // 4 fp32
using short4v = __attribute__((ext_vector_type(4))) short;  // 4 bf16 (8B)
using int4v   = __attribute__((ext_vector_type(4))) int;
using float4v = __attribute__((ext_vector_type(4))) float;
using float2v = __attribute__((ext_vector_type(2))) float;
using uint2v  = __attribute__((ext_vector_type(2))) unsigned;

static __device__ inline short f2bf(float f) {
    union { float f; unsigned u; } v; v.f = f;
    unsigned r = v.u + 0x7fffu + ((v.u >> 16) & 1u);
    return (short)(r >> 16);
}

// ---------- kernel 1: prep = transpose x -> BHWC bf16 | repack weight ----
__global__ __launch_bounds__(256) void prep_kernel(const float* __restrict__ x,
                                                   const float* __restrict__ wsrc,
                                                   short* __restrict__ xb16,
                                                   short* __restrict__ wtb) {
    int bidx = blockIdx.x;
    int tid  = threadIdx.x;
    if (bidx < 1024) {
        __shared__ float tile[64][65];
        int b   = bidx >> 8;
        int rem = bidx & 255;
        int c0  = (rem >> 6) * 64;
        int p0  = (rem & 63) * 64;
        int tp = tid & 63, tc = tid >> 6;
        for (int i = 0; i < 16; ++i) {
            int c = tc + i * 4;
            tile[c][tp] = x[(b * CN + c0 + c) * HWN + p0 + tp];
        }
        __syncthreads();
        int tcc = tid & 63, tpp = tid >> 6;
        for (int i = 0; i < 16; ++i) {
            int p = tpp + i * 4;
            xb16[(b * HWN + p0 + p) * CN + c0 + tcc] = f2bf(tile[tcc][p]);
        }
    } else {
        int chunk = (bidx - 1024) * 256 + tid;   // < 4*288*64 = 73728
        int ob  = chunk / (KC * 64);
        int rem = chunk - ob * (KC * 64);
        int kc  = rem >> 6;
        int row = rem & 63;
        int o   = ob * 64 + row;
        int kk  = kc >> 5;
        int oct = kc & 31;
        frag_ab v;
        #pragma unroll
        for (int e = 0; e < 8; ++e)
            v[e] = f2bf(wsrc[(o * CN + oct * 8 + e) * 9 + kk]);
        *(frag_ab*)&wtb[(size_t)chunk * 8] = v;
    }
}

// ---------- kernel 2: fused sample + GEMM ----------
// block: 32 m-rows (m0 = bid*32) x 256 o-cols, 8 waves (wave wv: cols
// wv*32..+32, sample rows wv*4..+4). Per kk:
//   issue B(kk,ks0/ks1) -> combine(kk) -> prefetch_x(kk+1) ->
//   lgkmcnt(0)+s_barrier (NO vmcnt drain) -> MFMA with bfx 2-ahead ring.
__global__ __launch_bounds__(512, 4) void fused_kernel(const short* __restrict__ xb16,
                                                       const short* __restrict__ wtb,
                                                       const float* __restrict__ offs,
                                                       const float* __restrict__ maskp,
                                                       float* __restrict__ out) {
    __shared__ struct {
        union {
            short Ab[2][8448];        // 2 x 16.5 KB A-tile (padded chunks)
            float outb[32 * 257];     // epilogue transpose, pad 257
        } mix;
        int desc[2304];               // 9 kk x 32 m x 8 dwords = 9216 B
    } sm;
    int tid  = threadIdx.x;
    int m0   = blockIdx.x * 32;
    int b    = m0 >> 12;
    int h    = (m0 >> 6) & 63;
    int w0   = m0 & 63;               // 0 or 32
    int wv   = __builtin_amdgcn_readfirstlane(tid >> 6);   // 0..7
    int lane = tid & 63;
    int q    = lane >> 4, r = lane & 15;
    // sampling write base (shorts): chunk 33*(lane>>1), half (lane&1)
    int wbase = 33 * (lane >> 1) * 8 + (lane & 1) * 4;
    int lane4 = lane * 4;
    int wv4   = wv * 4;

    // ---- one-time descriptor compute: thread t<288 -> desc (kk, m) ----
    if (tid < 288) {
        int kk = tid >> 5;
        int m  = tid & 31;
        int wc = w0 + m;
        int p  = h * 64 + wc;
        int ki = kk / 3, kj = kk - ki * 3;
        float dy = offs[(b * 18 + 2 * kk) * HWN + p];
        float dx = offs[(b * 18 + 2 * kk + 1) * HWN + p];
        float mv = maskp[(b * 9 + kk) * HWN + p];
        float py = (float)(h - 1 + ki) + dy;
        float px = (float)(wc - 1 + kj) + dx;
        float y0f = floorf(py), x0f = floorf(px);
        float wy = py - y0f, wx = px - x0f;
        int y0 = (int)y0f, x0 = (int)x0f;
        int4v cb; float4v cw;
        #pragma unroll
        for (int cy = 0; cy < 2; ++cy)
            #pragma unroll
            for (int cx = 0; cx < 2; ++cx) {
                int yy = y0 + cy, xx = x0 + cx;
                bool valid = (yy >= 0 && yy < HN && xx >= 0 && xx < WN);
                int yc = min(max(yy, 0), HN - 1);
                int xc = min(max(xx, 0), WN - 1);
                cb[cy * 2 + cx] = ((b * HN + yc) * WN + xc) * CN;
                float wgt = (cy ? wy : 1.f - wy) * (cx ? wx : 1.f - wx) * mv;
                cw[cy * 2 + cx] = valid ? wgt : 0.f;
            }
        int* dd = &sm.desc[tid * 8];
        *(int4v*)dd       = cb;
        *(float4v*)(dd + 4) = cw;
    }
    __syncthreads();

    frag_cd acc[2][2];
    #pragma unroll
    for (int i = 0; i < 2; ++i)
        #pragma unroll
        for (int j = 0; j < 2; ++j)
            acc[i][j] = (frag_cd){0.f, 0.f, 0.f, 0.f};

    short4v stg[4][4];    // prefetched corner rows (32 VGPR)
    float4v cwc[4];       // corner weights for the prefetched kk

    auto prefetch = [&](int kk1) {
        #pragma unroll
        for (int i = 0; i < 4; ++i) {
            int dbase = (kk1 * 32 + wv4 + i) * 8;     // wave-uniform -> bcast
            int4v cb = *(const int4v*)&sm.desc[dbase];
            cwc[i]   = *(const float4v*)&sm.desc[dbase + 4];
            #pragma unroll
            for (int c = 0; c < 4; ++c)               // coalesced 512B rows
                stg[i][c] = *(const short4v*)&xb16[cb[c] + lane4];
        }
    };

    int jb = (wv & 1) * 2;        // col sub-pair within the 64-col group
    int ob = wv >> 1;             // 64-col group 0..3
    auto ld_bf = [&](int kk, int ks, int j) {
        return *(const frag_ab*)
            &wtb[(((size_t)ob * KC + kk * 32 + ks * 4 + q) * 64
                  + (jb + j) * 16 + r) * 8];
    };

    prefetch(0);

    for (int kk = 0; kk < KKN; ++kk) {
        short* dst = sm.mix.Ab[kk & 1];
        // ---- B pipeline head: issue ks0/ks1 B-loads BEFORE combine so
        // they are OLDER than stg(kk+1) and have the whole combine+barrier
        // interval in flight.
        frag_ab bfx[2][2];
        #pragma unroll
        for (int j = 0; j < 2; ++j) {
            bfx[0][j] = ld_bf(kk, 0, j);
            bfx[1][j] = ld_bf(kk, 1, j);
        }
        // ---- combine phase: weighted 4-corner sum -> bf16 A-tile ----
        #pragma unroll
        for (int i = 0; i < 4; ++i) {
            float4v cw = cwc[i];
            short4v res;
            #pragma unroll
            for (int g = 0; g < 2; ++g) {             // channel pairs
                float2v a = (float2v){0.f, 0.f};
                #pragma unroll
                for (int c = 0; c < 4; ++c) {
                    uint2v uv = __builtin_bit_cast(uint2v, stg[i][c]);
                    unsigned uu = uv[g];
                    float2v f;
                    f.x = __builtin_bit_cast(float, uu << 16);
                    f.y = __builtin_bit_cast(float, uu & 0xffff0000u);
                    a += f * cw[c];
                }
                __hip_bfloat162 p2 = __float22bfloat162_rn(make_float2(a.x, a.y));
                res[2 * g]     = *(short*)&p2.x;
                res[2 * g + 1] = *(short*)&p2.y;
            }
            *(short4v*)&dst[wbase + (wv4 + i) * 8] = res;   // ds_write_b64
        }
        // ---- T14: issue next kk's gathers; they stay in flight ACROSS
        // the barrier (no vmcnt drain) and hide under the MFMA phase.
        if (kk < 8) prefetch(kk + 1);
        // ---- non-draining barrier: LDS ordering only ----
        asm volatile("s_waitcnt lgkmcnt(0)" ::: "memory");
        __builtin_amdgcn_s_barrier();
        asm volatile("" ::: "memory");
        // ---- MFMA phase: 8 k16-steps; A from LDS, B via 2-ahead ring ----
        #pragma unroll
        for (int ks = 0; ks < 8; ++ks) {
            const int cur = ks & 1;
            frag_ab af[2];
            #pragma unroll
            for (int i = 0; i < 2; ++i)
                af[i] = *(const frag_ab*)
                    &dst[(33 * (ks * 4 + q) + i * 16 + r) * 8];
            __builtin_amdgcn_s_setprio(1);
            #pragma unroll
            for (int i = 0; i < 2; ++i)
                #pragma unroll
                for (int j = 0; j < 2; ++j)
                    acc[i][j] = __builtin_amdgcn_mfma_f32_16x16x32_bf16(
                        af[i], bfx[cur][j], acc[i][j], 0, 0, 0);
            __builtin_amdgcn_s_setprio(0);
            if (ks < 6) {
                #pragma unroll
                for (int j = 0; j < 2; ++j)
                    bfx[cur][j] = ld_bf(kk, ks + 2, j);
            }
        }
        // no trailing barrier: next kk writes the other buffer; the barrier
        // at kk+1 orders mfma(kk) before any combine(kk+2) buffer reuse.
    }
    __syncthreads();

    // ---- epilogue: acc (row=i*16+q*4+reg, col=wv*32+j*16+r) -> LDS -> BOHW
    #pragma unroll
    for (int i = 0; i < 2; ++i)
        #pragma unroll
        for (int j = 0; j < 2; ++j) {
            int ml = i * 16 + q * 4;
            int ol = wv * 32 + j * 16 + r;
            sm.mix.outb[(ml + 0) * 257 + ol] = acc[i][j][0];
            sm.mix.outb[(ml + 1) * 257 + ol] = acc[i][j][1];
            sm.mix.outb[(ml + 2) * 257 + ol] = acc[i][j][2];
            sm.mix.outb[(ml + 3) * 257 + ol] = acc[i][j][3];
        }
    __syncthreads();
    {
        int ww = tid & 31;        // width within tile
        int og = tid >> 5;        // 0..15
        #pragma unroll
        for (int oo = 0; oo < 16; ++oo) {
            int o = oo * 16 + og;
            out[(((size_t)b * ON + o) * HN + h) * WN + w0 + ww] =
                sm.mix.outb[ww * 257 + o];
        }
    }
}

extern "C" void kernel_launch(void* const* d_in, const int* in_sizes, int n_in,
                              void* d_out, int out_size, void* d_ws, size_t ws_size,
                              hipStream_t stream) {
    const float* x      = (const float*)d_in[0];
    const float* offset = (const float*)d_in[1];
    const float* mask   = (const float*)d_in[2];
    const float* weight = (const float*)d_in[3];
    float* out = (float*)d_out;

    // ws: xb16 bf16 8 MiB | wtb (B') bf16 1.125 MiB
    short* xb16 = (short*)d_ws;
    short* wtb  = (short*)((char*)d_ws + 8388608);

    hipLaunchKernelGGL(prep_kernel,  dim3(1312), dim3(256), 0, stream,
                       x, weight, xb16, wtb);
    hipLaunchKernelGGL(fused_kernel, dim3(512),  dim3(512), 0, stream,
                       xb16, wtb, offset, mask, out);
}

// Round 5
// 117.719 us; speedup vs baseline: 1.1635x; 1.0063x over previous
//
#include <hip/hip_runtime.h>
#include <hip/hip_bf16.h>

// Problem: x(4,256,64,64), offset(4,18,64,64), mask(4,9,64,64),
// weight(256,256,3,3) -> out(4,256,64,64). stride=1, pad=1, K=3.
// R15: 64-row M-tile (1024 thr, 16 waves) to halve B L2 traffic.
// R14 post-mortem (miss): VGPR stayed 56 -> compiler kept loads at use;
// pipelining gained 3us only. Traffic model: B panel (wtb 1.125MiB) read
// once per block from L2 = 590MB at 512 blocks (~17us of L2 BW) + 302MB
// gathers. B traffic scales 1/M-tile -> 64-row blocks (256 blocks, 1/CU,
// 4 waves/SIMD). Wave = 64x16 col-stripe: acc 4x1, ONE B-frag per ks
// shared by 4 MFMAs (no duplication: 16 waves x 8KB/kk = 128KB = exact
// per-kk B slice). A-tile chunk stride 65 (odd; same bank math as 33).
// Epilogue rows fully contiguous (w0=0). Keep: non-draining barriers,
// T14 x-prefetch, bfx ring, setprio, in-kernel desc (576/block).
#define CN 256
#define HN 64
#define WN 64
#define ON 256
#define KKN 9
#define HWN 4096
#define KDIM 2304   // 9*256
#define KC 288      // KDIM/8 chunks

using frag_ab = __attribute__((ext_vector_type(8))) short;  // 8 bf16
using frag_cd = __attribute__((ext_vector_type(4))) float;  // 4 fp32
using short4v = __attribute__((ext_vector_type(4))) short;  // 4 bf16 (8B)
using int4v   = __attribute__((ext_vector_type(4))) int;
using float4v = __attribute__((ext_vector_type(4))) float;
using float2v = __attribute__((ext_vector_type(2))) float;
using uint2v  = __attribute__((ext_vector_type(2))) unsigned;

static __device__ inline short f2bf(float f) {
    union { float f; unsigned u; } v; v.f = f;
    unsigned r = v.u + 0x7fffu + ((v.u >> 16) & 1u);
    return (short)(r >> 16);
}

// ---------- kernel 1: prep = transpose x -> BHWC bf16 | repack weight ----
__global__ __launch_bounds__(256) void prep_kernel(const float* __restrict__ x,
                                                   const float* __restrict__ wsrc,
                                                   short* __restrict__ xb16,
                                                   short* __restrict__ wtb) {
    int bidx = blockIdx.x;
    int tid  = threadIdx.x;
    if (bidx < 1024) {
        __shared__ float tile[64][65];
        int b   = bidx >> 8;
        int rem = bidx & 255;
        int c0  = (rem >> 6) * 64;
        int p0  = (rem & 63) * 64;
        int tp = tid & 63, tc = tid >> 6;
        for (int i = 0; i < 16; ++i) {
            int c = tc + i * 4;
            tile[c][tp] = x[(b * CN + c0 + c) * HWN + p0 + tp];
        }
        __syncthreads();
        int tcc = tid & 63, tpp = tid >> 6;
        for (int i = 0; i < 16; ++i) {
            int p = tpp + i * 4;
            xb16[(b * HWN + p0 + p) * CN + c0 + tcc] = f2bf(tile[tcc][p]);
        }
    } else {
        int chunk = (bidx - 1024) * 256 + tid;   // < 4*288*64 = 73728
        int ob  = chunk / (KC * 64);
        int rem = chunk - ob * (KC * 64);
        int kc  = rem >> 6;
        int row = rem & 63;
        int o   = ob * 64 + row;
        int kk  = kc >> 5;
        int oct = kc & 31;
        frag_ab v;
        #pragma unroll
        for (int e = 0; e < 8; ++e)
            v[e] = f2bf(wsrc[(o * CN + oct * 8 + e) * 9 + kk]);
        *(frag_ab*)&wtb[(size_t)chunk * 8] = v;
    }
}

// ---------- kernel 2: fused sample + GEMM ----------
// block: 64 m-rows (= one (b,h) row, w=0..63) x 256 o-cols, 16 waves.
// wave wv: col-stripe wv*16..+16 (acc 4x1), sample rows wv*4..+4.
// Per kk: issue B(ks0/ks1) -> combine -> prefetch_x(kk+1) ->
// lgkmcnt(0)+s_barrier (no vmcnt drain) -> 8 ks x {4 ds_read A, 4 MFMA
// sharing 1 B-frag, reload B ks+2}.
__global__ __launch_bounds__(1024, 4) void fused_kernel(const short* __restrict__ xb16,
                                                        const short* __restrict__ wtb,
                                                        const float* __restrict__ offs,
                                                        const float* __restrict__ maskp,
                                                        float* __restrict__ out) {
    __shared__ struct {
        union {
            short Ab[2][16640];       // 2 x 32.5 KB A-tile (stride-65 chunks)
            float outb[64 * 257];     // epilogue transpose, pad 257
        } mix;
        int desc[4608];               // 9 kk x 64 m x 8 dwords = 18 KB
    } sm;
    int tid  = threadIdx.x;
    int m0   = blockIdx.x * 64;
    int b    = m0 >> 12;
    int h    = (m0 >> 6) & 63;        // block = full (b,h) row, w 0..63
    int wv   = __builtin_amdgcn_readfirstlane(tid >> 6);   // 0..15
    int lane = tid & 63;
    int q    = lane >> 4, r = lane & 15;
    // sampling write base (shorts): chunk 65*(lane>>1), half (lane&1)
    int wbase = 65 * (lane >> 1) * 8 + (lane & 1) * 4;
    int lane4 = lane * 4;
    int wv4   = wv * 4;

    // ---- one-time descriptor compute: thread t<576 -> desc (kk, m) ----
    if (tid < 576) {
        int kk = tid >> 6;
        int m  = tid & 63;            // = w
        int p  = h * 64 + m;
        int ki = kk / 3, kj = kk - ki * 3;
        float dy = offs[(b * 18 + 2 * kk) * HWN + p];
        float dx = offs[(b * 18 + 2 * kk + 1) * HWN + p];
        float mv = maskp[(b * 9 + kk) * HWN + p];
        float py = (float)(h - 1 + ki) + dy;
        float px = (float)(m - 1 + kj) + dx;
        float y0f = floorf(py), x0f = floorf(px);
        float wy = py - y0f, wx = px - x0f;
        int y0 = (int)y0f, x0 = (int)x0f;
        int4v cb; float4v cw;
        #pragma unroll
        for (int cy = 0; cy < 2; ++cy)
            #pragma unroll
            for (int cx = 0; cx < 2; ++cx) {
                int yy = y0 + cy, xx = x0 + cx;
                bool valid = (yy >= 0 && yy < HN && xx >= 0 && xx < WN);
                int yc = min(max(yy, 0), HN - 1);
                int xc = min(max(xx, 0), WN - 1);
                cb[cy * 2 + cx] = ((b * HN + yc) * WN + xc) * CN;
                float wgt = (cy ? wy : 1.f - wy) * (cx ? wx : 1.f - wx) * mv;
                cw[cy * 2 + cx] = valid ? wgt : 0.f;
            }
        int* dd = &sm.desc[tid * 8];
        *(int4v*)dd       = cb;
        *(float4v*)(dd + 4) = cw;
    }
    __syncthreads();

    frag_cd acc[4];
    #pragma unroll
    for (int i = 0; i < 4; ++i)
        acc[i] = (frag_cd){0.f, 0.f, 0.f, 0.f};

    short4v stg[4][4];    // prefetched corner rows (32 VGPR)
    float4v cwc[4];       // corner weights for the prefetched kk

    auto prefetch = [&](int kk1) {
        #pragma unroll
        for (int i = 0; i < 4; ++i) {
            int dbase = (kk1 * 64 + wv4 + i) * 8;     // wave-uniform -> bcast
            int4v cb = *(const int4v*)&sm.desc[dbase];
            cwc[i]   = *(const float4v*)&sm.desc[dbase + 4];
            #pragma unroll
            for (int c = 0; c < 4; ++c)               // coalesced 512B rows
                stg[i][c] = *(const short4v*)&xb16[cb[c] + lane4];
        }
    };

    int ob   = wv >> 2;               // 64-col group 0..3
    int orow = (wv & 3) * 16;         // row-in-group base (+r)
    auto ld_bf = [&](int kk, int ks) {
        return *(const frag_ab*)
            &wtb[(((size_t)ob * KC + kk * 32 + ks * 4 + q) * 64
                  + orow + r) * 8];
    };

    prefetch(0);

    for (int kk = 0; kk < KKN; ++kk) {
        short* dst = sm.mix.Ab[kk & 1];
        // ---- B pipeline head: ks0/ks1 issued before combine (older than
        // stg(kk+1); in-order vmcnt => bf waits don't drain stg).
        frag_ab bfx[2];
        bfx[0] = ld_bf(kk, 0);
        bfx[1] = ld_bf(kk, 1);
        // ---- combine phase: weighted 4-corner sum -> bf16 A-tile ----
        #pragma unroll
        for (int i = 0; i < 4; ++i) {
            float4v cw = cwc[i];
            short4v res;
            #pragma unroll
            for (int g = 0; g < 2; ++g) {             // channel pairs
                float2v a = (float2v){0.f, 0.f};
                #pragma unroll
                for (int c = 0; c < 4; ++c) {
                    uint2v uv = __builtin_bit_cast(uint2v, stg[i][c]);
                    unsigned uu = uv[g];
                    float2v f;
                    f.x = __builtin_bit_cast(float, uu << 16);
                    f.y = __builtin_bit_cast(float, uu & 0xffff0000u);
                    a += f * cw[c];
                }
                __hip_bfloat162 p2 = __float22bfloat162_rn(make_float2(a.x, a.y));
                res[2 * g]     = *(short*)&p2.x;
                res[2 * g + 1] = *(short*)&p2.y;
            }
            *(short4v*)&dst[wbase + (wv4 + i) * 8] = res;   // ds_write_b64
        }
        // ---- T14: next kk's gathers stay in flight ACROSS the barrier ----
        if (kk < 8) prefetch(kk + 1);
        // ---- non-draining barrier: LDS ordering only ----
        asm volatile("s_waitcnt lgkmcnt(0)" ::: "memory");
        __builtin_amdgcn_s_barrier();
        asm volatile("" ::: "memory");
        // ---- MFMA phase: 8 k16-steps; A from LDS, 1 B-frag -> 4 MFMA ----
        #pragma unroll
        for (int ks = 0; ks < 8; ++ks) {
            const int cur = ks & 1;
            frag_ab af[4];
            #pragma unroll
            for (int i = 0; i < 4; ++i)
                af[i] = *(const frag_ab*)
                    &dst[(65 * (ks * 4 + q) + i * 16 + r) * 8];
            __builtin_amdgcn_s_setprio(1);
            #pragma unroll
            for (int i = 0; i < 4; ++i)
                acc[i] = __builtin_amdgcn_mfma_f32_16x16x32_bf16(
                    af[i], bfx[cur], acc[i], 0, 0, 0);
            __builtin_amdgcn_s_setprio(0);
            if (ks < 6)
                bfx[cur] = ld_bf(kk, ks + 2);
        }
        // no trailing barrier: next kk writes the other buffer; the barrier
        // at kk+1 orders mfma(kk) before any combine(kk+2) buffer reuse.
    }
    __syncthreads();

    // ---- epilogue: acc (row=i*16+q*4+reg, col=wv*16+r) -> LDS -> BOHW ----
    #pragma unroll
    for (int i = 0; i < 4; ++i) {
        int ml = i * 16 + q * 4;
        int ol = wv * 16 + r;
        sm.mix.outb[(ml + 0) * 257 + ol] = acc[i][0];
        sm.mix.outb[(ml + 1) * 257 + ol] = acc[i][1];
        sm.mix.outb[(ml + 2) * 257 + ol] = acc[i][2];
        sm.mix.outb[(ml + 3) * 257 + ol] = acc[i][3];
    }
    __syncthreads();
    {
        int ww = tid & 63;        // w within row
        int og = tid >> 6;        // 0..15
        #pragma unroll
        for (int oo = 0; oo < 16; ++oo) {
            int o = oo * 16 + og;
            out[(((size_t)b * ON + o) * HN + h) * WN + ww] =
                sm.mix.outb[ww * 257 + o];
        }
    }
}

extern "C" void kernel_launch(void* const* d_in, const int* in_sizes, int n_in,
                              void* d_out, int out_size, void* d_ws, size_t ws_size,
                              hipStream_t stream) {
    const float* x      = (const float*)d_in[0];
    const float* offset = (const float*)d_in[1];
    const float* mask   = (const float*)d_in[2];
    const float* weight = (const float*)d_in[3];
    float* out = (float*)d_out;

    // ws: xb16 bf16 8 MiB | wtb (B') bf16 1.125 MiB
    short* xb16 = (short*)d_ws;
    short* wtb  = (short*)((char*)d_ws + 8388608);

    hipLaunchKernelGGL(prep_kernel,  dim3(1312), dim3(256),  0, stream,
                       x, weight, xb16, wtb);
    hipLaunchKernelGGL(fused_kernel, dim3(256),  dim3(1024), 0, stream,
                       xb16, wtb, offset, mask, out);
}